// Round 11
// baseline (111.129 us; speedup 1.0000x reference)
//
#include <hip/hip_runtime.h>

// Fredkin6Layer, algebraically reduced to 9 coefs/gate:
//   a = x[b, (3g+1..3g+3) & 4095],  w = softmax(wgts[g])
//   o0 = (w0+w1)a0 + (w2+w3)a1 + (w4+w5)a2
//   o1 = (w3+w5)a0 + (w1+w4)a1 + (w0+w2)a2
//        + (w0-w1+w2-w3)a0a1 + (w1-w0+w4-w5)a0a2 + (w3-w2+w5-w4)a1a2
//   o2 = (a0+a1+a2) - o0 - o1
//
// R9 base (2 blocks/CU, 16 rows/block, 3-buffer register pipeline) +
// NONTEMPORAL output stores (via native ext_vector type: the builtin
// rejects HIP_vector_type). out has zero reuse -> bypass L2 write-
// allocate to kill residual dirty-line write inflation (119 vs 101 MB).

constexpr int DIN  = 4096;
constexpr int NG   = 2048;
constexpr int DOUT = 3 * NG;   // 6144
constexpr int GPB  = 1024;     // gates per block tile
constexpr int GPT  = 4;        // gates per thread
constexpr int NRB  = 256;      // row-tile blocks per gate half
constexpr int RPT  = 4;        // rows per tile
constexpr int TPB  = 4;        // tiles per block (stride NRB)
constexpr int NIT  = TPB * RPT;            // 16 rows per block
constexpr int ROWSTEP = RPT * NRB;         // 1024 rows between tiles

using f32x4 = __attribute__((ext_vector_type(4))) float;

__global__ __launch_bounds__(256, 2) void fredkin_kernel(
    const float* __restrict__ x,
    const float* __restrict__ wgts,
    float* __restrict__ out)
{
    const int tid  = threadIdx.x;
    const int gt   = blockIdx.x >> 8;        // gate half; pair (b, b+256) ->
    const int rb   = blockIdx.x & (NRB - 1); //   same XCD (256 % 8 == 0)
    const int g0   = gt * GPB;
    const int base = 3 * g0;                 // 0 or 3072
    const int row0 = rb * RPT;

    // ---- per-thread input window: 4 aligned float4 at cols (base+12t+4k)&4095 ----
    const int jb = 12 * tid;
    const float4* xp0; const float4* xp1; const float4* xp2; const float4* xp3;
    {
        int c0 = (base + jb +  0) & (DIN - 1);
        int c1 = (base + jb +  4) & (DIN - 1);
        int c2 = (base + jb +  8) & (DIN - 1);
        int c3 = (base + jb + 12) & (DIN - 1);
        xp0 = reinterpret_cast<const float4*>(x + c0);
        xp1 = reinterpret_cast<const float4*>(x + c1);
        xp2 = reinterpret_cast<const float4*>(x + c2);
        xp3 = reinterpret_cast<const float4*>(x + c3);
    }
    const size_t rs4 = DIN / 4;              // float4 per x row

    // row for iteration i: row0 + (i>>2)*ROWSTEP + (i&3)
    // 3-buffer register rotation, fully unrolled -> all indices static.
    float4 buf[3][4];

    // issue rows 0 and 1 BEFORE the exp-heavy coef math (overlap HBM latency)
    {
        size_t ro = (size_t)row0 * rs4;
        buf[0][0] = xp0[ro]; buf[0][1] = xp1[ro];
        buf[0][2] = xp2[ro]; buf[0][3] = xp3[ro];
        size_t r1 = ro + rs4;
        buf[1][0] = xp0[r1]; buf[1][1] = xp1[r1];
        buf[1][2] = xp2[r1]; buf[1][3] = xp3[r1];
    }

    // ---- per-thread coefficients for its 4 gates (softmax in registers) ----
    float cw[GPT][3], dl[GPT][3], qc[GPT][3];
    {
        const float4* wp =
            reinterpret_cast<const float4*>(wgts + (size_t)(g0 + GPT * tid) * 6);
        float4 h0 = wp[0], h1 = wp[1], h2 = wp[2], h3 = wp[3], h4 = wp[4], h5 = wp[5];
        float w[24] = {h0.x,h0.y,h0.z,h0.w, h1.x,h1.y,h1.z,h1.w,
                       h2.x,h2.y,h2.z,h2.w, h3.x,h3.y,h3.z,h3.w,
                       h4.x,h4.y,h4.z,h4.w, h5.x,h5.y,h5.z,h5.w};
        #pragma unroll
        for (int u = 0; u < GPT; ++u) {
            const float* ww = &w[6 * u];
            float m = fmaxf(fmaxf(fmaxf(ww[0], ww[1]), fmaxf(ww[2], ww[3])),
                            fmaxf(ww[4], ww[5]));
            float e0 = __expf(ww[0] - m), e1 = __expf(ww[1] - m),
                  e2 = __expf(ww[2] - m), e3 = __expf(ww[3] - m),
                  e4 = __expf(ww[4] - m), e5 = __expf(ww[5] - m);
            float inv = 1.0f / (e0 + e1 + e2 + e3 + e4 + e5);
            e0 *= inv; e1 *= inv; e2 *= inv; e3 *= inv; e4 *= inv; e5 *= inv;
            cw[u][0] = e0 + e1; cw[u][1] = e2 + e3; cw[u][2] = e4 + e5;
            dl[u][0] = e3 + e5; dl[u][1] = e1 + e4; dl[u][2] = e0 + e2;
            qc[u][0] = e0 - e1 + e2 - e3;
            qc[u][1] = e1 - e0 + e4 - e5;
            qc[u][2] = e3 - e2 + e5 - e4;
        }
    }

    float* ob = out + (size_t)row0 * DOUT + base + jb;

    #pragma unroll
    for (int i = 0; i < NIT; ++i) {
        const int cur = i % 3;
        // prefetch row i+2 into the buffer freed two iters ago
        if (i + 2 < NIT) {
            const int nx = (i + 2) % 3;
            const int dn = ((i + 2) >> 2) * ROWSTEP + ((i + 2) & 3);
            size_t ro = (size_t)(row0 + dn) * rs4;
            buf[nx][0] = xp0[ro]; buf[nx][1] = xp1[ro];
            buf[nx][2] = xp2[ro]; buf[nx][3] = xp3[ro];
        }

        float4 f0 = buf[cur][0], f1 = buf[cur][1],
               f2 = buf[cur][2], f3 = buf[cur][3];

        float a[GPT][3] = { {f0.y, f0.z, f0.w},
                            {f1.x, f1.y, f1.z},
                            {f1.w, f2.x, f2.y},
                            {f2.z, f2.w, f3.x} };
        float o[12];
        #pragma unroll
        for (int u = 0; u < GPT; ++u) {
            float a0 = a[u][0], a1 = a[u][1], a2 = a[u][2];
            float p01 = a0 * a1, p02 = a0 * a2, p12 = a1 * a2;
            float t0 = cw[u][0] * a0 + cw[u][1] * a1 + cw[u][2] * a2;
            float qq = qc[u][0] * p01 + qc[u][1] * p02 + qc[u][2] * p12;
            float t1 = dl[u][0] * a0 + dl[u][1] * a1 + dl[u][2] * a2 + qq;
            float t2 = (a0 + a1 + a2) - t0 - t1;
            o[3*u + 0] = t0; o[3*u + 1] = t1; o[3*u + 2] = t2;
        }

        const int di = (i >> 2) * ROWSTEP + (i & 3);
        // streaming (nontemporal) stores via native clang vector type:
        // out has zero reuse, keep it out of L2.
        f32x4* op4 = reinterpret_cast<f32x4*>(ob + (size_t)di * DOUT);
        f32x4 s0 = {o[0], o[1], o[2],  o[3]};
        f32x4 s1 = {o[4], o[5], o[6],  o[7]};
        f32x4 s2 = {o[8], o[9], o[10], o[11]};
        __builtin_nontemporal_store(s0, op4 + 0);
        __builtin_nontemporal_store(s1, op4 + 1);
        __builtin_nontemporal_store(s2, op4 + 2);
    }
}

extern "C" void kernel_launch(void* const* d_in, const int* in_sizes, int n_in,
                              void* d_out, int out_size, void* d_ws, size_t ws_size,
                              hipStream_t stream) {
    const float* x    = (const float*)d_in[0];   // (4096, 4096) f32
    const float* wgts = (const float*)d_in[1];   // (2048, 6)   f32
    // d_in[2] = connections — deterministic (3g+1+k) % DIN, not needed.
    float* out = (float*)d_out;                  // (4096, 6144) f32

    const int grid = 2 * NRB;                    // 512 blocks = 2 per CU
    fredkin_kernel<<<grid, 256, 0, stream>>>(x, wgts, out);
}

// Round 12
// 42.369 us; speedup vs baseline: 2.6229x; 2.6229x over previous
//
#include <hip/hip_runtime.h>

// Fredkin6Layer, algebraically reduced to 9 coefs/gate:
//   a = x[b, (3g+1..3g+3) & 4095],  w = softmax(wgts[g])
//   o0 = (w0+w1)a0 + (w2+w3)a1 + (w4+w5)a2
//   o1 = (w3+w5)a0 + (w1+w4)a1 + (w0+w2)a2
//        + (w0-w1+w2-w3)a0a1 + (w1-w0+w4-w5)a0a2 + (w3-w2+w5-w4)a1a2
//   o2 = (a0+a1+a2) - o0 - o1
//
// R9 long-stream register-pipeline structure at MODERATE concurrency:
// 1024 blocks = 4/CU, 8 rows/block. Tests whether the long-stream
// structure holds write inflation ~1.2x while pipe BW rises toward the
// ~4.4 TB/s seen at higher concurrency. NT stores reverted: R11 showed
// nt bypasses L2 write-combining on gfx950 (WRITE 119->225 MB, 2.7x time).

constexpr int DIN  = 4096;
constexpr int NG   = 2048;
constexpr int DOUT = 3 * NG;   // 6144
constexpr int GPB  = 1024;     // gates per block tile
constexpr int GPT  = 4;        // gates per thread
constexpr int NRB  = 512;      // row-tile blocks per gate half
constexpr int RPT  = 4;        // consecutive rows per tile
constexpr int TPB  = 2;        // tiles per block (stride NRB*RPT)
constexpr int NIT  = TPB * RPT;            // 8 rows per block
constexpr int ROWSTEP = RPT * NRB;         // 2048 rows between tiles

__global__ __launch_bounds__(256, 4) void fredkin_kernel(
    const float* __restrict__ x,
    const float* __restrict__ wgts,
    float* __restrict__ out)
{
    const int tid  = threadIdx.x;
    const int gt   = blockIdx.x >> 9;        // gate half; pair (b, b+512) ->
    const int rb   = blockIdx.x & (NRB - 1); //   same XCD (512 % 8 == 0)
    const int g0   = gt * GPB;
    const int base = 3 * g0;                 // 0 or 3072
    const int row0 = rb * RPT;

    // ---- per-thread input window: 4 aligned float4 at cols (base+12t+4k)&4095 ----
    const int jb = 12 * tid;
    const float4* xp0; const float4* xp1; const float4* xp2; const float4* xp3;
    {
        int c0 = (base + jb +  0) & (DIN - 1);
        int c1 = (base + jb +  4) & (DIN - 1);
        int c2 = (base + jb +  8) & (DIN - 1);
        int c3 = (base + jb + 12) & (DIN - 1);
        xp0 = reinterpret_cast<const float4*>(x + c0);
        xp1 = reinterpret_cast<const float4*>(x + c1);
        xp2 = reinterpret_cast<const float4*>(x + c2);
        xp3 = reinterpret_cast<const float4*>(x + c3);
    }
    const size_t rs4 = DIN / 4;              // float4 per x row

    // row for iteration i: row0 + (i>>2)*ROWSTEP + (i&3)
    // 3-buffer register rotation, fully unrolled -> all indices static.
    float4 buf[3][4];

    // issue rows 0 and 1 BEFORE the exp-heavy coef math (overlap HBM latency)
    {
        size_t ro = (size_t)row0 * rs4;
        buf[0][0] = xp0[ro]; buf[0][1] = xp1[ro];
        buf[0][2] = xp2[ro]; buf[0][3] = xp3[ro];
        size_t r1 = ro + rs4;
        buf[1][0] = xp0[r1]; buf[1][1] = xp1[r1];
        buf[1][2] = xp2[r1]; buf[1][3] = xp3[r1];
    }

    // ---- per-thread coefficients for its 4 gates (softmax in registers) ----
    float cw[GPT][3], dl[GPT][3], qc[GPT][3];
    {
        const float4* wp =
            reinterpret_cast<const float4*>(wgts + (size_t)(g0 + GPT * tid) * 6);
        float4 h0 = wp[0], h1 = wp[1], h2 = wp[2], h3 = wp[3], h4 = wp[4], h5 = wp[5];
        float w[24] = {h0.x,h0.y,h0.z,h0.w, h1.x,h1.y,h1.z,h1.w,
                       h2.x,h2.y,h2.z,h2.w, h3.x,h3.y,h3.z,h3.w,
                       h4.x,h4.y,h4.z,h4.w, h5.x,h5.y,h5.z,h5.w};
        #pragma unroll
        for (int u = 0; u < GPT; ++u) {
            const float* ww = &w[6 * u];
            float m = fmaxf(fmaxf(fmaxf(ww[0], ww[1]), fmaxf(ww[2], ww[3])),
                            fmaxf(ww[4], ww[5]));
            float e0 = __expf(ww[0] - m), e1 = __expf(ww[1] - m),
                  e2 = __expf(ww[2] - m), e3 = __expf(ww[3] - m),
                  e4 = __expf(ww[4] - m), e5 = __expf(ww[5] - m);
            float inv = 1.0f / (e0 + e1 + e2 + e3 + e4 + e5);
            e0 *= inv; e1 *= inv; e2 *= inv; e3 *= inv; e4 *= inv; e5 *= inv;
            cw[u][0] = e0 + e1; cw[u][1] = e2 + e3; cw[u][2] = e4 + e5;
            dl[u][0] = e3 + e5; dl[u][1] = e1 + e4; dl[u][2] = e0 + e2;
            qc[u][0] = e0 - e1 + e2 - e3;
            qc[u][1] = e1 - e0 + e4 - e5;
            qc[u][2] = e3 - e2 + e5 - e4;
        }
    }

    float* ob = out + (size_t)row0 * DOUT + base + jb;

    #pragma unroll
    for (int i = 0; i < NIT; ++i) {
        const int cur = i % 3;
        // prefetch row i+2 into the buffer freed two iters ago
        if (i + 2 < NIT) {
            const int nx = (i + 2) % 3;
            const int dn = ((i + 2) >> 2) * ROWSTEP + ((i + 2) & 3);
            size_t ro = (size_t)(row0 + dn) * rs4;
            buf[nx][0] = xp0[ro]; buf[nx][1] = xp1[ro];
            buf[nx][2] = xp2[ro]; buf[nx][3] = xp3[ro];
        }

        float4 f0 = buf[cur][0], f1 = buf[cur][1],
               f2 = buf[cur][2], f3 = buf[cur][3];

        float a[GPT][3] = { {f0.y, f0.z, f0.w},
                            {f1.x, f1.y, f1.z},
                            {f1.w, f2.x, f2.y},
                            {f2.z, f2.w, f3.x} };
        float o[12];
        #pragma unroll
        for (int u = 0; u < GPT; ++u) {
            float a0 = a[u][0], a1 = a[u][1], a2 = a[u][2];
            float p01 = a0 * a1, p02 = a0 * a2, p12 = a1 * a2;
            float t0 = cw[u][0] * a0 + cw[u][1] * a1 + cw[u][2] * a2;
            float qq = qc[u][0] * p01 + qc[u][1] * p02 + qc[u][2] * p12;
            float t1 = dl[u][0] * a0 + dl[u][1] * a1 + dl[u][2] * a2 + qq;
            float t2 = (a0 + a1 + a2) - t0 - t1;
            o[3*u + 0] = t0; o[3*u + 1] = t1; o[3*u + 2] = t2;
        }

        const int di = (i >> 2) * ROWSTEP + (i & 3);
        float4* op4 = reinterpret_cast<float4*>(ob + (size_t)di * DOUT);
        op4[0] = make_float4(o[0], o[1], o[2],  o[3]);
        op4[1] = make_float4(o[4], o[5], o[6],  o[7]);
        op4[2] = make_float4(o[8], o[9], o[10], o[11]);
    }
}

extern "C" void kernel_launch(void* const* d_in, const int* in_sizes, int n_in,
                              void* d_out, int out_size, void* d_ws, size_t ws_size,
                              hipStream_t stream) {
    const float* x    = (const float*)d_in[0];   // (4096, 4096) f32
    const float* wgts = (const float*)d_in[1];   // (2048, 6)   f32
    // d_in[2] = connections — deterministic (3g+1+k) % DIN, not needed.
    float* out = (float*)d_out;                  // (4096, 6144) f32

    const int grid = 2 * NRB;                    // 1024 blocks = 4 per CU
    fredkin_kernel<<<grid, 256, 0, stream>>>(x, wgts, out);
}

// Round 15
// 31.608 us; speedup vs baseline: 3.5158x; 1.3404x over previous
//
#include <hip/hip_runtime.h>

// Fredkin6Layer, algebraically reduced to 9 coefs/gate:
//   a = x[b, (3g+1..3g+3) & 4095],  w = softmax(wgts[g])
//   o0 = (w0+w1)a0 + (w2+w3)a1 + (w4+w5)a2
//   o1 = (w3+w5)a0 + (w1+w4)a1 + (w0+w2)a2
//        + (w0-w1+w2-w3)a0a1 + (w1-w0+w4-w5)a0a2 + (w3-w2+w5-w4)a1a2
//   o2 = (a0+a1+a2) - o0 - o1
//
// COALESCED-MAPPING variant, PURE C++ (no inline asm — R14's asm store
// never landed; outputs stayed zero). Thread (wv,l) owns gates
// {256wv+64u+l}, so per u the wave's inputs/outputs are 12B-per-lane
// CONTIGUOUS:
//   loads  = 1 align-4 dwordx4 per u (13 full lines, no partial-line tax)
//   stores = 3 adjacent scalar floats per u (LLVM merges to dwordx3 at
//            align 4; even unmerged, the wave's back-to-back dword
//            streams fully cover each 64B line -> write-combine friendly)
// vs the old 4-consecutive-gate mapping whose 48B lane stride partially
// touched 48 lines per store instr (measured ceiling 4.3 TB/s).
// Gate windows start at 3g+1 and 4096 % 3 == 1 -> no window straddles
// the x row-wrap; the lone f4 overrun (col 4093) is shift-selected.
// R9 frame: 512 blocks = 2/CU, 16 rows/block, 3-buffer register pipeline.

constexpr int DIN  = 4096;
constexpr int NG   = 2048;
constexpr int DOUT = 3 * NG;   // 6144
constexpr int GPB  = 1024;     // gates per block tile
constexpr int NRB  = 256;      // row-tile blocks per gate half
constexpr int RPT  = 4;        // consecutive rows per tile
constexpr int NIT  = 16;       // rows per block
constexpr int ROWSTEP = RPT * NRB;   // 1024

typedef float f4u __attribute__((ext_vector_type(4), aligned(4)));

__global__ __launch_bounds__(256, 2) void fredkin_kernel(
    const float* __restrict__ x,
    const float* __restrict__ wgts,
    float* __restrict__ out)
{
    const int tid = threadIdx.x;
    const int wv  = tid >> 6;
    const int l   = tid & 63;
    const int gt  = blockIdx.x >> 8;         // gate half; pair (b, b+256) ->
    const int rb  = blockIdx.x & (NRB - 1);  //   same XCD (256 % 8 == 0)
    const int g0  = gt * GPB;
    const int base = 3 * g0;                 // 0 or 3072
    const int row0 = rb * RPT;

    // per-u input column (constant across rows) + seam adjust:
    // col == 4093 is the only window whose f4 load would cross the row end
    // (window starts are ==1 mod 3 when unwrapped; wrapped starts < 2047).
    int col[4], adj[4];
    #pragma unroll
    for (int u = 0; u < 4; ++u) {
        int c = (base + 768 * wv + 192 * u + 3 * l + 1) & (DIN - 1);
        adj[u] = (c == 4093) ? 1 : 0;
        col[u] = c - adj[u];
    }
    const int obase = base + 768 * wv + 3 * l;   // output word, + 192u per u

    // ---- prefetch rows 0,1 before the exp-heavy coef math ----
    f4u buf[3][4];
    {
        const float* xr0 = x + (size_t)row0 * DIN;
        const float* xr1 = xr0 + DIN;
        #pragma unroll
        for (int u = 0; u < 4; ++u) {
            buf[0][u] = *(const f4u*)(xr0 + col[u]);
            buf[1][u] = *(const f4u*)(xr1 + col[u]);
        }
    }

    // ---- coefficients for the 4 owned gates: g = g0 + 256wv + 64u + l ----
    float cw[4][3], dl_[4][3], qc[4][3];
    #pragma unroll
    for (int u = 0; u < 4; ++u) {
        const int g = g0 + 256 * wv + 64 * u + l;
        const float2* wp = reinterpret_cast<const float2*>(wgts + 6 * g);
        float2 p0 = wp[0], p1 = wp[1], p2 = wp[2];
        float ww0 = p0.x, ww1 = p0.y, ww2 = p1.x,
              ww3 = p1.y, ww4 = p2.x, ww5 = p2.y;
        float m = fmaxf(fmaxf(fmaxf(ww0, ww1), fmaxf(ww2, ww3)),
                        fmaxf(ww4, ww5));
        float e0 = __expf(ww0 - m), e1 = __expf(ww1 - m),
              e2 = __expf(ww2 - m), e3 = __expf(ww3 - m),
              e4 = __expf(ww4 - m), e5 = __expf(ww5 - m);
        float inv = 1.0f / (e0 + e1 + e2 + e3 + e4 + e5);
        e0 *= inv; e1 *= inv; e2 *= inv; e3 *= inv; e4 *= inv; e5 *= inv;
        cw[u][0]  = e0 + e1; cw[u][1]  = e2 + e3; cw[u][2]  = e4 + e5;
        dl_[u][0] = e3 + e5; dl_[u][1] = e1 + e4; dl_[u][2] = e0 + e2;
        qc[u][0]  = e0 - e1 + e2 - e3;
        qc[u][1]  = e1 - e0 + e4 - e5;
        qc[u][2]  = e3 - e2 + e5 - e4;
    }

    #pragma unroll
    for (int i = 0; i < NIT; ++i) {
        const int cur = i % 3;
        const int drow = (i >> 2) * ROWSTEP + (i & 3);
        // prefetch row i+2 into the buffer freed two iters ago
        if (i + 2 < NIT) {
            const int nx = (i + 2) % 3;
            const int dn = ((i + 2) >> 2) * ROWSTEP + ((i + 2) & 3);
            const float* xr = x + (size_t)(row0 + dn) * DIN;
            #pragma unroll
            for (int u = 0; u < 4; ++u)
                buf[nx][u] = *(const f4u*)(xr + col[u]);
        }

        const size_t orow = (size_t)(row0 + drow) * DOUT;
        #pragma unroll
        for (int u = 0; u < 4; ++u) {
            f4u v = buf[cur][u];
            // seam lane loaded at col-1: take .yzw instead of .xyz
            float a0 = adj[u] ? v.y : v.x;
            float a1 = adj[u] ? v.z : v.y;
            float a2 = adj[u] ? v.w : v.z;

            float p01 = a0 * a1, p02 = a0 * a2, p12 = a1 * a2;
            float t0 = cw[u][0] * a0 + cw[u][1] * a1 + cw[u][2] * a2;
            float qq = qc[u][0] * p01 + qc[u][1] * p02 + qc[u][2] * p12;
            float t1 = dl_[u][0] * a0 + dl_[u][1] * a1 + dl_[u][2] * a2 + qq;
            float t2 = (a0 + a1 + a2) - t0 - t1;

            // 12B-contiguous per lane; wave covers 768B per u with full
            // line coverage. LLVM merges these into dwordx3 (align 4).
            float* op = out + (orow + (size_t)(obase + 192 * u));
            op[0] = t0;
            op[1] = t1;
            op[2] = t2;
        }
    }
}

extern "C" void kernel_launch(void* const* d_in, const int* in_sizes, int n_in,
                              void* d_out, int out_size, void* d_ws, size_t ws_size,
                              hipStream_t stream) {
    const float* x    = (const float*)d_in[0];   // (4096, 4096) f32
    const float* wgts = (const float*)d_in[1];   // (2048, 6)   f32
    // d_in[2] = connections — deterministic (3g+1+k) % DIN, not needed.
    float* out = (float*)d_out;                  // (4096, 6144) f32

    const int grid = 2 * NRB;                    // 512 blocks = 2 per CU
    fredkin_kernel<<<grid, 256, 0, stream>>>(x, wgts, out);
}